// Round 13
// baseline (96.177 us; speedup 1.0000x reference)
//
#include <hip/hip_runtime.h>
#include <hip/hip_bf16.h>
#include <math.h>

#define BATCH 4096
#define CTX 20
#define DIM 128
#define NSAMP 8192
#define NCHUNK 64   // 8192 / 128 column-chunks in the GEMM kernel

typedef __attribute__((ext_vector_type(8))) short short8;
typedef __attribute__((ext_vector_type(4))) float f32x4;

__device__ __forceinline__ unsigned short f2bf(float x) {
    union { float f; unsigned u; } v; v.f = x;
    unsigned r = v.u + 0x7FFFu + ((v.u >> 16) & 1u);   // round-to-nearest-even
    return (unsigned short)(r >> 16);
}

// ---- Eigen plog<float>, EXACT op schedule (GenericPacketMathFunctions.h).
// Poly steps are pmadd (= vfmadd, fused). Tail ops are pmul/padd/psub —
// SEPARATE roundings, never contracted, and -0.5*x2 is subtracted from x
// BEFORE y is added (association differs from R11/R12's fused variants):
//   y1 = e*q1; tmp = 0.5*x2; y = y+y1; x = x-tmp; y2 = e*q2; x = x+y; x = x+y2
// This is also XLA-CPU's GenerateVF32Log / MLIR LogApproximation lineage.
__device__ __forceinline__ float eigen_plogf(float xf) {
    union { float f; unsigned u; } v; v.f = xf;    // x >= 1, normal, finite
    int ei = (int)((v.u >> 23) & 0xFFu) - 126;     // pfrexp: x = m*2^e, m in [0.5,1)
    v.u = (v.u & 0x007FFFFFu) | 0x3F000000u;
    float x = v.f;
    float e = (float)ei;
    bool msk = x < 0.707106781186547524f;          // x < SQRTHF
    float tmp = msk ? x : 0.0f;                    // pand(x, mask)
    x = __fsub_rn(x, 1.0f);
    e = __fsub_rn(e, msk ? 1.0f : 0.0f);
    x = __fadd_rn(x, tmp);

    float x2 = __fmul_rn(x, x);
    float x3 = __fmul_rn(x2, x);

    float y, y1, y2;
    y  = __builtin_fmaf( 7.0376836292E-2f, x, -1.1514610310E-1f);  // p0,p1
    y1 = __builtin_fmaf(-1.2420140846E-1f, x,  1.4249322787E-1f);  // p3,p4
    y2 = __builtin_fmaf( 2.0000714765E-1f, x, -2.4999993993E-1f);  // p6,p7
    y  = __builtin_fmaf(y,  x,  1.1676998740E-1f);                 // +p2
    y1 = __builtin_fmaf(y1, x, -1.6668057665E-1f);                 // +p5
    y2 = __builtin_fmaf(y2, x,  3.3333331174E-1f);                 // +p8
    y  = __builtin_fmaf(y,  x3, y1);
    y  = __builtin_fmaf(y,  x3, y2);
    y  = __fmul_rn(y, x3);                         // pmul

    y1  = __fmul_rn(e, -2.12194440e-4f);           // pmul (q1) — NOT fused
    tmp = __fmul_rn(x2, 0.5f);                     // pmul — NOT fused
    y   = __fadd_rn(y, y1);                        // padd
    x   = __fsub_rn(x, tmp);                       // psub (x first!)
    y2  = __fmul_rn(e, 0.693359375f);              // pmul (q2) — NOT fused
    x   = __fadd_rn(x, y);                         // padd
    x   = __fadd_rn(x, y2);                        // padd
    return x;
}

// f32 log-uniform correction reproducing the np reference: the l2-l1
// cancellation amplifies the log's pointwise bits ~2^20x via the label term;
// log1p/expm1/final log are smooth (any ~1-ulp impl agrees to ~1e-7 in lec)
// and the sampled-side terms are ~700x softmax-attenuated.
__device__ __forceinline__ float log_expected_count(int id) {
    float idf = (float)id;                           // exact (id < 2^24)
    float l2 = eigen_plogf(__fadd_rn(idf, 2.0f));
    float l1 = eigen_plogf(__fadd_rn(idf, 1.0f));
    float num = __fsub_rn(l2, l1);                   // the f32 cancellation
    float logH = eigen_plogf(1000001.0f);
    float p = num / logH;
    float t = __fmul_rn(8192.0f, log1pf(-p));        // *2^13 exact
    float e = -expm1f(t);
    e = fmaxf(e, 1e-38f);                            // finite-diagnostic guard
    return logf(e);
}

// ---- kernel 1: h[b] = sum_ctx input_emb[ids[b,c]]; store bf16; fused true logit
__global__ void k_prep_h(const int* __restrict__ ids, const int* __restrict__ labels,
                         const float* __restrict__ in_emb, const float* __restrict__ out_emb,
                         const float* __restrict__ bias,
                         unsigned short* __restrict__ h_bf, float* __restrict__ tl) {
    int b = blockIdx.x;
    int lane = threadIdx.x;           // 64 threads, each owns dims {2*lane, 2*lane+1}
    float ax = 0.f, ay = 0.f;
#pragma unroll
    for (int c = 0; c < CTX; ++c) {
        int id = ids[b * CTX + c];
        const float2 v = ((const float2*)(in_emb + (size_t)id * DIM))[lane];
        ax += v.x; ay += v.y;
    }
    ushort2 hb; hb.x = f2bf(ax); hb.y = f2bf(ay);
    ((ushort2*)(h_bf + (size_t)b * DIM))[lane] = hb;

    int lab = labels[b];
    const float2 w = ((const float2*)(out_emb + (size_t)lab * DIM))[lane];
    float prod = ax * w.x + ay * w.y;
#pragma unroll
    for (int m = 32; m > 0; m >>= 1) prod += __shfl_xor(prod, m, 64);
    if (lane == 0) tl[b] = prod + bias[lab] - log_expected_count(lab);
}

// ---- kernel 2: gather sampled rows -> bf16; adjusted sampled bias
__global__ void k_prep_w(const int* __restrict__ sampled, const float* __restrict__ out_emb,
                         const float* __restrict__ bias,
                         unsigned short* __restrict__ w_bf, float* __restrict__ sb) {
    int s = blockIdx.x;
    int lane = threadIdx.x;           // 64
    int sid = sampled[s];
    const float2 v = ((const float2*)(out_emb + (size_t)sid * DIM))[lane];
    ushort2 wb; wb.x = f2bf(v.x); wb.y = f2bf(v.y);
    ((ushort2*)(w_bf + (size_t)s * DIM))[lane] = wb;
    if (lane == 0) sb[s] = bias[sid] - log_expected_count(sid);
}

// ---- kernel 3: bf16 MFMA GEMM [4096x128]x[8192x128]^T fused with
//      bias add, accidental-hit mask, exp, and per-row partial sums.
__global__ __launch_bounds__(256) void k_gemm_lse(
    const unsigned short* __restrict__ h_bf, const unsigned short* __restrict__ w_bf,
    const float* __restrict__ sb, const int* __restrict__ sampled,
    const int* __restrict__ labels, float* __restrict__ partials) {
    int lane = threadIdx.x & 63;
    int wv   = threadIdx.x >> 6;
    int rbase = blockIdx.x * 64 + wv * 16;
    int cbase = blockIdx.y * 128;
    int r16 = lane & 15;              // A-row / B-row (=col) within 16
    int kg  = lane >> 4;              // k-group 0..3

    short8 a[4];
    const unsigned short* ap = h_bf + (size_t)(rbase + r16) * DIM + kg * 8;
#pragma unroll
    for (int ks = 0; ks < 4; ++ks) a[ks] = *(const short8*)(ap + ks * 32);

    f32x4 acc[8];
#pragma unroll
    for (int t = 0; t < 8; ++t) acc[t] = (f32x4){0.f, 0.f, 0.f, 0.f};

#pragma unroll
    for (int t = 0; t < 8; ++t) {
        const unsigned short* bp = w_bf + (size_t)(cbase + t * 16 + r16) * DIM + kg * 8;
#pragma unroll
        for (int ks = 0; ks < 4; ++ks) {
            short8 bv = *(const short8*)(bp + ks * 32);
            acc[t] = __builtin_amdgcn_mfma_f32_16x16x32_bf16(a[ks], bv, acc[t], 0, 0, 0);
        }
    }

    int lab[4]; int grow[4];
    float rsum[4] = {0.f, 0.f, 0.f, 0.f};
#pragma unroll
    for (int r = 0; r < 4; ++r) {
        grow[r] = rbase + kg * 4 + r;            // C/D row = (lane>>4)*4 + reg
        lab[r]  = labels[grow[r]];
    }
#pragma unroll
    for (int t = 0; t < 8; ++t) {
        int col = cbase + t * 16 + r16;          // C/D col = lane&15
        float sbv = sb[col];
        int   sid = sampled[col];
#pragma unroll
        for (int r = 0; r < 4; ++r) {
            float logit = acc[t][r] + sbv;
            float e = (sid == lab[r]) ? 0.f : __expf(logit);
            rsum[r] += e;
        }
    }
#pragma unroll
    for (int m = 1; m < 16; m <<= 1) {
#pragma unroll
        for (int r = 0; r < 4; ++r) rsum[r] += __shfl_xor(rsum[r], m, 64);
    }
    if (r16 == 0) {
#pragma unroll
        for (int r = 0; r < 4; ++r)
            partials[(size_t)grow[r] * NCHUNK + blockIdx.y] = rsum[r];
    }
}

// ---- kernel 4: loss[b] = log(sum_chunks + exp(tl)) - tl
__global__ void k_reduce(const float* __restrict__ partials, const float* __restrict__ tl,
                         float* __restrict__ out) {
    int row  = blockIdx.x * 4 + (threadIdx.x >> 6);
    int lane = threadIdx.x & 63;
    float s = partials[(size_t)row * NCHUNK + lane];
#pragma unroll
    for (int m = 32; m > 0; m >>= 1) s += __shfl_xor(s, m, 64);
    if (lane == 0) {
        float t = tl[row];
        out[row] = logf(s + __expf(t)) - t;
    }
}

extern "C" void kernel_launch(void* const* d_in, const int* in_sizes, int n_in,
                              void* d_out, int out_size, void* d_ws, size_t ws_size,
                              hipStream_t stream) {
    const int*   ids     = (const int*)d_in[0];   // integers arrive as int32
    const int*   labels  = (const int*)d_in[1];
    const int*   sampled = (const int*)d_in[2];
    const float* in_emb  = (const float*)d_in[3];
    const float* out_emb = (const float*)d_in[4];
    const float* bias    = (const float*)d_in[5];
    float* out = (float*)d_out;

    char* ws = (char*)d_ws;
    unsigned short* h_bf = (unsigned short*)(ws);                       // 1 MB
    unsigned short* w_bf = (unsigned short*)(ws + (1u << 20));          // 2 MB
    float* tl       = (float*)(ws + 3u * (1u << 20));                   // 16 KB
    float* sb       = (float*)(ws + 3u * (1u << 20) + (1u << 16));      // 32 KB
    float* partials = (float*)(ws + 3u * (1u << 20) + (1u << 16) + (1u << 15)); // 1 MB

    k_prep_h<<<dim3(BATCH), dim3(64), 0, stream>>>(ids, labels, in_emb, out_emb, bias, h_bf, tl);
    k_prep_w<<<dim3(NSAMP), dim3(64), 0, stream>>>(sampled, out_emb, bias, w_bf, sb);
    k_gemm_lse<<<dim3(64, 64), dim3(256), 0, stream>>>(h_bf, w_bf, sb, sampled, labels, partials);
    k_reduce<<<dim3(BATCH / 4), dim3(256), 0, stream>>>(partials, tl, out);
}

// Round 14
// 38.788 us; speedup vs baseline: 2.4795x; 2.4795x over previous
//
#include <hip/hip_runtime.h>
#include <hip/hip_bf16.h>
#include <math.h>

#define BATCH 4096
#define CTX 20
#define DIM 128
#define NSAMP 8192
#define NCHUNK 64   // 8192 / 128 column-chunks in the GEMM kernel

typedef __attribute__((ext_vector_type(8))) short short8;
typedef __attribute__((ext_vector_type(4))) float f32x4;

__device__ __forceinline__ unsigned short f2bf(float x) {
    union { float f; unsigned u; } v; v.f = x;
    unsigned r = v.u + 0x7FFFu + ((v.u >> 16) & 1u);   // round-to-nearest-even
    return (unsigned short)(r >> 16);
}

// ---- Eigen plog<float>, EXACT op schedule — VERIFIED BIT-MATCH vs the
// harness np reference (R13 pass). DO NOT TOUCH.
__device__ __forceinline__ float eigen_plogf(float xf) {
    union { float f; unsigned u; } v; v.f = xf;    // x >= 1, normal, finite
    int ei = (int)((v.u >> 23) & 0xFFu) - 126;     // pfrexp: x = m*2^e, m in [0.5,1)
    v.u = (v.u & 0x007FFFFFu) | 0x3F000000u;
    float x = v.f;
    float e = (float)ei;
    bool msk = x < 0.707106781186547524f;          // x < SQRTHF
    float tmp = msk ? x : 0.0f;                    // pand(x, mask)
    x = __fsub_rn(x, 1.0f);
    e = __fsub_rn(e, msk ? 1.0f : 0.0f);
    x = __fadd_rn(x, tmp);

    float x2 = __fmul_rn(x, x);
    float x3 = __fmul_rn(x2, x);

    float y, y1, y2;
    y  = __builtin_fmaf( 7.0376836292E-2f, x, -1.1514610310E-1f);  // p0,p1
    y1 = __builtin_fmaf(-1.2420140846E-1f, x,  1.4249322787E-1f);  // p3,p4
    y2 = __builtin_fmaf( 2.0000714765E-1f, x, -2.4999993993E-1f);  // p6,p7
    y  = __builtin_fmaf(y,  x,  1.1676998740E-1f);                 // +p2
    y1 = __builtin_fmaf(y1, x, -1.6668057665E-1f);                 // +p5
    y2 = __builtin_fmaf(y2, x,  3.3333331174E-1f);                 // +p8
    y  = __builtin_fmaf(y,  x3, y1);
    y  = __builtin_fmaf(y,  x3, y2);
    y  = __fmul_rn(y, x3);                         // pmul

    y1  = __fmul_rn(e, -2.12194440e-4f);           // pmul (q1) — NOT fused
    tmp = __fmul_rn(x2, 0.5f);                     // pmul — NOT fused
    y   = __fadd_rn(y, y1);                        // padd
    x   = __fsub_rn(x, tmp);                       // psub (x first!)
    y2  = __fmul_rn(e, 0.693359375f);              // pmul (q2) — NOT fused
    x   = __fadd_rn(x, y);                         // padd
    x   = __fadd_rn(x, y2);                        // padd
    return x;
}

__device__ __forceinline__ float log_expected_count(int id) {
    float idf = (float)id;                           // exact (id < 2^24)
    float l2 = eigen_plogf(__fadd_rn(idf, 2.0f));
    float l1 = eigen_plogf(__fadd_rn(idf, 1.0f));
    float num = __fsub_rn(l2, l1);                   // the f32 cancellation
    float logH = eigen_plogf(1000001.0f);
    float p = num / logH;
    float t = __fmul_rn(8192.0f, log1pf(-p));        // *2^13 exact
    float e = -expm1f(t);
    e = fmaxf(e, 1e-38f);
    return logf(e);
}

// Fragment layout: element (row, k) of a [N x 128] bf16 matrix lives at
// ushort offset ((row>>4)*4 + (k>>5))*512 + (((k>>3)&3)*16 + (row&15))*8 + (k&7).
// A wave's MFMA load for (tile, ks) is then ONE coalesced 1KB read at
// (tile*4+ks)*512 + lane*8.

// ---- kernel 1: h[b] = sum_ctx input_emb[ids[b,c]]; store bf16 fragment; true logit
__global__ void k_prep_h(const int* __restrict__ ids, const int* __restrict__ labels,
                         const float* __restrict__ in_emb, const float* __restrict__ out_emb,
                         const float* __restrict__ bias,
                         unsigned short* __restrict__ h_frag, float* __restrict__ tl) {
    int b = blockIdx.x;
    int lane = threadIdx.x;           // 64 threads, each owns dims {2*lane, 2*lane+1}
    float ax = 0.f, ay = 0.f;
#pragma unroll
    for (int c = 0; c < CTX; ++c) {
        int id = ids[b * CTX + c];
        const float2 v = ((const float2*)(in_emb + (size_t)id * DIM))[lane];
        ax += v.x; ay += v.y;
    }
    ushort2 hb; hb.x = f2bf(ax); hb.y = f2bf(ay);
    int k0 = 2 * lane;
    int ks = k0 >> 5, kgf = (k0 >> 3) & 3, j = k0 & 7;
    size_t off = (size_t)(((b >> 4) * 4 + ks) * 512) + (kgf * 16 + (b & 15)) * 8 + j;
    *(ushort2*)(h_frag + off) = hb;

    int lab = labels[b];
    const float2 w = ((const float2*)(out_emb + (size_t)lab * DIM))[lane];
    float prod = ax * w.x + ay * w.y;
#pragma unroll
    for (int m = 32; m > 0; m >>= 1) prod += __shfl_xor(prod, m, 64);
    if (lane == 0) tl[b] = prod + bias[lab] - log_expected_count(lab);
}

// ---- kernel 2: gather sampled rows -> bf16 fragment; adjusted sampled bias
__global__ void k_prep_w(const int* __restrict__ sampled, const float* __restrict__ out_emb,
                         const float* __restrict__ bias,
                         unsigned short* __restrict__ w_frag, float* __restrict__ sb) {
    int s = blockIdx.x;
    int lane = threadIdx.x;           // 64
    int sid = sampled[s];
    const float2 v = ((const float2*)(out_emb + (size_t)sid * DIM))[lane];
    ushort2 wb; wb.x = f2bf(v.x); wb.y = f2bf(v.y);
    int k0 = 2 * lane;
    int ks = k0 >> 5, kgf = (k0 >> 3) & 3, j = k0 & 7;
    size_t off = (size_t)(((s >> 4) * 4 + ks) * 512) + (kgf * 16 + (s & 15)) * 8 + j;
    *(ushort2*)(w_frag + off) = wb;
    if (lane == 0) sb[s] = bias[sid] - log_expected_count(sid);
}

// ---- kernel 3: 128x128-tile bf16 MFMA GEMM fused with bias/mask/exp/row-sums.
//      4 waves x 32 rows; B slice (32KB) staged in LDS; all loads coalesced 1KB.
__global__ __launch_bounds__(256) void k_gemm_lse(
    const unsigned short* __restrict__ h_frag, const unsigned short* __restrict__ w_frag,
    const float* __restrict__ sb, const int* __restrict__ sampled,
    const int* __restrict__ labels, float* __restrict__ partials) {
    __shared__ __align__(16) unsigned short ldsb[16384];   // 32KB
    int tid  = threadIdx.x;
    int lane = tid & 63;
    int wv   = tid >> 6;
    int r16  = lane & 15;
    int kg   = lane >> 4;
    int rbase = blockIdx.x * 128 + wv * 32;
    int cbase = blockIdx.y * 128;

    // stage B: w_frag ushorts [cbase*128, +16384) -> LDS (linear, lane-contiguous)
    const unsigned short* wsrc = w_frag + (size_t)cbase * 128;
#pragma unroll
    for (int i = 0; i < 8; ++i) {
        size_t o = (size_t)(i * 256 + tid) * 8;
        *(short8*)(ldsb + o) = *(const short8*)(wsrc + o);
    }

    // A fragments: 2 row-tiles x 4 ks, coalesced
    short8 a[2][4];
#pragma unroll
    for (int rt = 0; rt < 2; ++rt)
#pragma unroll
        for (int ks = 0; ks < 4; ++ks)
            a[rt][ks] = *(const short8*)(h_frag +
                (size_t)((((rbase >> 4) + rt) * 4 + ks) * 512) + lane * 8);

    f32x4 acc[2][8];
#pragma unroll
    for (int rt = 0; rt < 2; ++rt)
#pragma unroll
        for (int t = 0; t < 8; ++t) acc[rt][t] = (f32x4){0.f, 0.f, 0.f, 0.f};

    __syncthreads();
#pragma unroll
    for (int t = 0; t < 8; ++t) {
#pragma unroll
        for (int ks = 0; ks < 4; ++ks) {
            short8 bv = *(const short8*)(ldsb + (t * 4 + ks) * 512 + lane * 8);
            acc[0][t] = __builtin_amdgcn_mfma_f32_16x16x32_bf16(a[0][ks], bv, acc[0][t], 0, 0, 0);
            acc[1][t] = __builtin_amdgcn_mfma_f32_16x16x32_bf16(a[1][ks], bv, acc[1][t], 0, 0, 0);
        }
    }

    int lab[2][4]; int grow[2][4];
    float rsum[2][4];
#pragma unroll
    for (int rt = 0; rt < 2; ++rt)
#pragma unroll
        for (int r = 0; r < 4; ++r) {
            grow[rt][r] = rbase + rt * 16 + kg * 4 + r;   // C/D row = (lane>>4)*4+reg
            lab[rt][r]  = labels[grow[rt][r]];
            rsum[rt][r] = 0.f;
        }
#pragma unroll
    for (int t = 0; t < 8; ++t) {
        int col = cbase + t * 16 + r16;                   // C/D col = lane&15
        float sbv = sb[col];
        int   sid = sampled[col];
#pragma unroll
        for (int rt = 0; rt < 2; ++rt)
#pragma unroll
            for (int r = 0; r < 4; ++r) {
                float logit = acc[rt][t][r] + sbv;
                if (sid != lab[rt][r]) rsum[rt][r] += __expf(logit);
            }
    }
#pragma unroll
    for (int m = 1; m < 16; m <<= 1)
#pragma unroll
        for (int rt = 0; rt < 2; ++rt)
#pragma unroll
            for (int r = 0; r < 4; ++r)
                rsum[rt][r] += __shfl_xor(rsum[rt][r], m, 64);
    if (r16 == 0)
#pragma unroll
        for (int rt = 0; rt < 2; ++rt)
#pragma unroll
            for (int r = 0; r < 4; ++r)
                partials[(size_t)grow[rt][r] * NCHUNK + blockIdx.y] = rsum[rt][r];
}

// ---- kernel 4: loss[b] = log(sum_chunks + exp(tl)) - tl
__global__ void k_reduce(const float* __restrict__ partials, const float* __restrict__ tl,
                         float* __restrict__ out) {
    int row  = blockIdx.x * 4 + (threadIdx.x >> 6);
    int lane = threadIdx.x & 63;
    float s = partials[(size_t)row * NCHUNK + lane];
#pragma unroll
    for (int m = 32; m > 0; m >>= 1) s += __shfl_xor(s, m, 64);
    if (lane == 0) {
        float t = tl[row];
        out[row] = logf(s + __expf(t)) - t;
    }
}

extern "C" void kernel_launch(void* const* d_in, const int* in_sizes, int n_in,
                              void* d_out, int out_size, void* d_ws, size_t ws_size,
                              hipStream_t stream) {
    const int*   ids     = (const int*)d_in[0];   // integers arrive as int32
    const int*   labels  = (const int*)d_in[1];
    const int*   sampled = (const int*)d_in[2];
    const float* in_emb  = (const float*)d_in[3];
    const float* out_emb = (const float*)d_in[4];
    const float* bias    = (const float*)d_in[5];
    float* out = (float*)d_out;

    char* ws = (char*)d_ws;
    unsigned short* h_frag = (unsigned short*)(ws);                     // 1 MB
    unsigned short* w_frag = (unsigned short*)(ws + (1u << 20));        // 2 MB
    float* tl       = (float*)(ws + 3u * (1u << 20));                   // 16 KB
    float* sb       = (float*)(ws + 3u * (1u << 20) + (1u << 16));      // 32 KB
    float* partials = (float*)(ws + 3u * (1u << 20) + (1u << 16) + (1u << 15)); // 1 MB

    k_prep_h<<<dim3(BATCH), dim3(64), 0, stream>>>(ids, labels, in_emb, out_emb, bias, h_frag, tl);
    k_prep_w<<<dim3(NSAMP), dim3(64), 0, stream>>>(sampled, out_emb, bias, w_frag, sb);
    k_gemm_lse<<<dim3(BATCH / 128, NSAMP / 128), dim3(256), 0, stream>>>(h_frag, w_frag, sb, sampled, labels, partials);
    k_reduce<<<dim3(BATCH / 4), dim3(256), 0, stream>>>(partials, tl, out);
}

// Round 15
// 36.754 us; speedup vs baseline: 2.6168x; 1.0554x over previous
//
#include <hip/hip_runtime.h>
#include <hip/hip_bf16.h>
#include <math.h>

#define BATCH 4096
#define CTX 20
#define DIM 128
#define NSAMP 8192
#define NCHUNK 64   // 8192 / 128 column-chunks in the GEMM kernel

typedef __attribute__((ext_vector_type(8))) short short8;
typedef __attribute__((ext_vector_type(4))) float f32x4;

__device__ __forceinline__ unsigned short f2bf(float x) {
    union { float f; unsigned u; } v; v.f = x;
    unsigned r = v.u + 0x7FFFu + ((v.u >> 16) & 1u);   // round-to-nearest-even
    return (unsigned short)(r >> 16);
}

// ---- Eigen plog<float>, EXACT op schedule — VERIFIED BIT-MATCH vs the
// harness np reference (R13 pass). DO NOT TOUCH.
__device__ __forceinline__ float eigen_plogf(float xf) {
    union { float f; unsigned u; } v; v.f = xf;    // x >= 1, normal, finite
    int ei = (int)((v.u >> 23) & 0xFFu) - 126;     // pfrexp: x = m*2^e, m in [0.5,1)
    v.u = (v.u & 0x007FFFFFu) | 0x3F000000u;
    float x = v.f;
    float e = (float)ei;
    bool msk = x < 0.707106781186547524f;          // x < SQRTHF
    float tmp = msk ? x : 0.0f;                    // pand(x, mask)
    x = __fsub_rn(x, 1.0f);
    e = __fsub_rn(e, msk ? 1.0f : 0.0f);
    x = __fadd_rn(x, tmp);

    float x2 = __fmul_rn(x, x);
    float x3 = __fmul_rn(x2, x);

    float y, y1, y2;
    y  = __builtin_fmaf( 7.0376836292E-2f, x, -1.1514610310E-1f);  // p0,p1
    y1 = __builtin_fmaf(-1.2420140846E-1f, x,  1.4249322787E-1f);  // p3,p4
    y2 = __builtin_fmaf( 2.0000714765E-1f, x, -2.4999993993E-1f);  // p6,p7
    y  = __builtin_fmaf(y,  x,  1.1676998740E-1f);                 // +p2
    y1 = __builtin_fmaf(y1, x, -1.6668057665E-1f);                 // +p5
    y2 = __builtin_fmaf(y2, x,  3.3333331174E-1f);                 // +p8
    y  = __builtin_fmaf(y,  x3, y1);
    y  = __builtin_fmaf(y,  x3, y2);
    y  = __fmul_rn(y, x3);                         // pmul

    y1  = __fmul_rn(e, -2.12194440e-4f);           // pmul (q1) — NOT fused
    tmp = __fmul_rn(x2, 0.5f);                     // pmul — NOT fused
    y   = __fadd_rn(y, y1);                        // padd
    x   = __fsub_rn(x, tmp);                       // psub (x first!)
    y2  = __fmul_rn(e, 0.693359375f);              // pmul (q2) — NOT fused
    x   = __fadd_rn(x, y);                         // padd
    x   = __fadd_rn(x, y2);                        // padd
    return x;
}

__device__ __forceinline__ float log_expected_count(int id) {
    float idf = (float)id;                           // exact (id < 2^24)
    float l2 = eigen_plogf(__fadd_rn(idf, 2.0f));
    float l1 = eigen_plogf(__fadd_rn(idf, 1.0f));
    float num = __fsub_rn(l2, l1);                   // the f32 cancellation
    float logH = eigen_plogf(1000001.0f);
    float p = num / logH;
    float t = __fmul_rn(8192.0f, log1pf(-p));        // *2^13 exact
    float e = -expm1f(t);
    e = fmaxf(e, 1e-38f);
    return logf(e);
}

// Fragment layout: element (row, k) of a [N x 128] bf16 matrix lives at
// ushort offset ((row>>4)*4 + (k>>5))*512 + (((k>>3)&3)*16 + (row&15))*8 + (k&7).
// A wave's MFMA load for (tile, ks) is ONE coalesced 1KB read at
// (tile*4+ks)*512 + lane*8.

// ---- kernel 1 (merged): block < BATCH: h[b] + true logit; else: w-gather + bias
__global__ void k_prep(const int* __restrict__ ids, const int* __restrict__ labels,
                       const int* __restrict__ sampled,
                       const float* __restrict__ in_emb, const float* __restrict__ out_emb,
                       const float* __restrict__ bias,
                       unsigned short* __restrict__ h_frag, unsigned short* __restrict__ w_frag,
                       float* __restrict__ tl, float* __restrict__ sb) {
    int lane = threadIdx.x;           // 64 threads, dims {2*lane, 2*lane+1}
    int k0 = 2 * lane;
    int ks = k0 >> 5, kgf = (k0 >> 3) & 3, j = k0 & 7;
    if (blockIdx.x < BATCH) {
        int b = blockIdx.x;
        float ax = 0.f, ay = 0.f;
#pragma unroll
        for (int c = 0; c < CTX; ++c) {
            int id = ids[b * CTX + c];
            const float2 v = ((const float2*)(in_emb + (size_t)id * DIM))[lane];
            ax += v.x; ay += v.y;
        }
        ushort2 hb; hb.x = f2bf(ax); hb.y = f2bf(ay);
        size_t off = (size_t)(((b >> 4) * 4 + ks) * 512) + (kgf * 16 + (b & 15)) * 8 + j;
        *(ushort2*)(h_frag + off) = hb;

        int lab = labels[b];
        const float2 w = ((const float2*)(out_emb + (size_t)lab * DIM))[lane];
        float prod = ax * w.x + ay * w.y;
#pragma unroll
        for (int m = 32; m > 0; m >>= 1) prod += __shfl_xor(prod, m, 64);
        if (lane == 0) tl[b] = prod + bias[lab] - log_expected_count(lab);
    } else {
        int s = blockIdx.x - BATCH;
        int sid = sampled[s];
        const float2 v = ((const float2*)(out_emb + (size_t)sid * DIM))[lane];
        ushort2 wb; wb.x = f2bf(v.x); wb.y = f2bf(v.y);
        size_t off = (size_t)(((s >> 4) * 4 + ks) * 512) + (kgf * 16 + (s & 15)) * 8 + j;
        *(ushort2*)(w_frag + off) = wb;
        if (lane == 0) sb[s] = bias[sid] - log_expected_count(sid);
    }
}

// ---- kernel 2: 256x128-tile bf16 MFMA GEMM fused with bias/mask/exp/row-sums.
//      4 waves x 64 rows (4 row-tiles) -> MFMA:ds_read = 4:1.
//      B slice (32KB) staged via global_load_lds (width 16).
__global__ __launch_bounds__(256, 2) void k_gemm_lse(
    const unsigned short* __restrict__ h_frag, const unsigned short* __restrict__ w_frag,
    const float* __restrict__ sb, const int* __restrict__ sampled,
    const int* __restrict__ labels, float* __restrict__ partials) {
    __shared__ __align__(16) unsigned short ldsb[16384];   // 32KB
    int tid  = threadIdx.x;
    int lane = tid & 63;
    int wv   = tid >> 6;
    int r16  = lane & 15;
    int kg   = lane >> 4;
    int rbase = blockIdx.x * 256 + wv * 64;
    int cbase = blockIdx.y * 128;

    // stage B via async global->LDS, 16B/lane, linear layout
    const unsigned short* wsrc = w_frag + (size_t)cbase * 128;
#pragma unroll
    for (int i = 0; i < 8; ++i) {
        int eo = (i * 256 + tid) * 8;            // ushort offset, lane-contiguous
        __builtin_amdgcn_global_load_lds(
            (const __attribute__((address_space(1))) unsigned int*)(wsrc + eo),
            (__attribute__((address_space(3))) unsigned int*)(ldsb + eo),
            16, 0, 0);
    }

    // A fragments: 4 row-tiles x 4 ks, coalesced 1KB wave-loads (L2-resident)
    short8 a[4][4];
#pragma unroll
    for (int rt = 0; rt < 4; ++rt)
#pragma unroll
        for (int ks = 0; ks < 4; ++ks)
            a[rt][ks] = *(const short8*)(h_frag +
                (size_t)((((rbase >> 4) + rt) * 4 + ks) * 512) + lane * 8);

    f32x4 acc[4][8];
#pragma unroll
    for (int rt = 0; rt < 4; ++rt)
#pragma unroll
        for (int t = 0; t < 8; ++t) acc[rt][t] = (f32x4){0.f, 0.f, 0.f, 0.f};

    __syncthreads();
#pragma unroll
    for (int t = 0; t < 8; ++t) {
#pragma unroll
        for (int ks = 0; ks < 4; ++ks) {
            short8 bv = *(const short8*)(ldsb + (t * 4 + ks) * 512 + lane * 8);
#pragma unroll
            for (int rt = 0; rt < 4; ++rt)
                acc[rt][t] = __builtin_amdgcn_mfma_f32_16x16x32_bf16(a[rt][ks], bv, acc[rt][t], 0, 0, 0);
        }
    }

    int lab[4][4];
    float rsum[4][4];
#pragma unroll
    for (int rt = 0; rt < 4; ++rt)
#pragma unroll
        for (int r = 0; r < 4; ++r) {
            lab[rt][r]  = labels[rbase + rt * 16 + kg * 4 + r];
            rsum[rt][r] = 0.f;
        }
#pragma unroll
    for (int t = 0; t < 8; ++t) {
        int col = cbase + t * 16 + r16;                   // C/D col = lane&15
        float sbv = sb[col];
        int   sid = sampled[col];
#pragma unroll
        for (int rt = 0; rt < 4; ++rt)
#pragma unroll
            for (int r = 0; r < 4; ++r) {
                float logit = acc[rt][t][r] + sbv;
                if (sid != lab[rt][r]) rsum[rt][r] += __expf(logit);
            }
    }
#pragma unroll
    for (int m = 1; m < 16; m <<= 1)
#pragma unroll
        for (int rt = 0; rt < 4; ++rt)
#pragma unroll
            for (int r = 0; r < 4; ++r)
                rsum[rt][r] += __shfl_xor(rsum[rt][r], m, 64);
    if (r16 == 0)
#pragma unroll
        for (int rt = 0; rt < 4; ++rt)
#pragma unroll
            for (int r = 0; r < 4; ++r)
                partials[(size_t)(rbase + rt * 16 + kg * 4 + r) * NCHUNK + blockIdx.y] = rsum[rt][r];
}

// ---- kernel 3: loss[b] = log(sum_chunks + exp(tl)) - tl
__global__ void k_reduce(const float* __restrict__ partials, const float* __restrict__ tl,
                         float* __restrict__ out) {
    int row  = blockIdx.x * 4 + (threadIdx.x >> 6);
    int lane = threadIdx.x & 63;
    float s = partials[(size_t)row * NCHUNK + lane];
#pragma unroll
    for (int m = 32; m > 0; m >>= 1) s += __shfl_xor(s, m, 64);
    if (lane == 0) {
        float t = tl[row];
        out[row] = logf(s + __expf(t)) - t;
    }
}

extern "C" void kernel_launch(void* const* d_in, const int* in_sizes, int n_in,
                              void* d_out, int out_size, void* d_ws, size_t ws_size,
                              hipStream_t stream) {
    const int*   ids     = (const int*)d_in[0];   // integers arrive as int32
    const int*   labels  = (const int*)d_in[1];
    const int*   sampled = (const int*)d_in[2];
    const float* in_emb  = (const float*)d_in[3];
    const float* out_emb = (const float*)d_in[4];
    const float* bias    = (const float*)d_in[5];
    float* out = (float*)d_out;

    char* ws = (char*)d_ws;
    unsigned short* h_frag = (unsigned short*)(ws);                     // 1 MB
    unsigned short* w_frag = (unsigned short*)(ws + (1u << 20));        // 2 MB
    float* tl       = (float*)(ws + 3u * (1u << 20));                   // 16 KB
    float* sb       = (float*)(ws + 3u * (1u << 20) + (1u << 16));      // 32 KB
    float* partials = (float*)(ws + 3u * (1u << 20) + (1u << 16) + (1u << 15)); // 1 MB

    k_prep<<<dim3(BATCH + NSAMP), dim3(64), 0, stream>>>(ids, labels, sampled, in_emb, out_emb, bias,
                                                         h_frag, w_frag, tl, sb);
    k_gemm_lse<<<dim3(BATCH / 256, NSAMP / 128), dim3(256), 0, stream>>>(h_frag, w_frag, sb, sampled, labels, partials);
    k_reduce<<<dim3(BATCH / 4), dim3(256), 0, stream>>>(partials, tl, out);
}

// Round 16
// 35.155 us; speedup vs baseline: 2.7358x; 1.0455x over previous
//
#include <hip/hip_runtime.h>
#include <hip/hip_bf16.h>
#include <math.h>

#define BATCH 4096
#define CTX 20
#define DIM 128
#define NSAMP 8192
#define NCHUNK 64   // 8192 / 128 column-chunks in the GEMM kernel

typedef __attribute__((ext_vector_type(8))) short short8;
typedef __attribute__((ext_vector_type(4))) float f32x4;

__device__ __forceinline__ unsigned short f2bf(float x) {
    union { float f; unsigned u; } v; v.f = x;
    unsigned r = v.u + 0x7FFFu + ((v.u >> 16) & 1u);   // round-to-nearest-even
    return (unsigned short)(r >> 16);
}

// ---- Eigen plog<float>, EXACT op schedule — VERIFIED BIT-MATCH vs the
// harness np reference (R13 pass). DO NOT TOUCH.
__device__ __forceinline__ float eigen_plogf(float xf) {
    union { float f; unsigned u; } v; v.f = xf;    // x >= 1, normal, finite
    int ei = (int)((v.u >> 23) & 0xFFu) - 126;     // pfrexp: x = m*2^e, m in [0.5,1)
    v.u = (v.u & 0x007FFFFFu) | 0x3F000000u;
    float x = v.f;
    float e = (float)ei;
    bool msk = x < 0.707106781186547524f;          // x < SQRTHF
    float tmp = msk ? x : 0.0f;                    // pand(x, mask)
    x = __fsub_rn(x, 1.0f);
    e = __fsub_rn(e, msk ? 1.0f : 0.0f);
    x = __fadd_rn(x, tmp);

    float x2 = __fmul_rn(x, x);
    float x3 = __fmul_rn(x2, x);

    float y, y1, y2;
    y  = __builtin_fmaf( 7.0376836292E-2f, x, -1.1514610310E-1f);  // p0,p1
    y1 = __builtin_fmaf(-1.2420140846E-1f, x,  1.4249322787E-1f);  // p3,p4
    y2 = __builtin_fmaf( 2.0000714765E-1f, x, -2.4999993993E-1f);  // p6,p7
    y  = __builtin_fmaf(y,  x,  1.1676998740E-1f);                 // +p2
    y1 = __builtin_fmaf(y1, x, -1.6668057665E-1f);                 // +p5
    y2 = __builtin_fmaf(y2, x,  3.3333331174E-1f);                 // +p8
    y  = __builtin_fmaf(y,  x3, y1);
    y  = __builtin_fmaf(y,  x3, y2);
    y  = __fmul_rn(y, x3);                         // pmul

    y1  = __fmul_rn(e, -2.12194440e-4f);           // pmul (q1) — NOT fused
    tmp = __fmul_rn(x2, 0.5f);                     // pmul — NOT fused
    y   = __fadd_rn(y, y1);                        // padd
    x   = __fsub_rn(x, tmp);                       // psub (x first!)
    y2  = __fmul_rn(e, 0.693359375f);              // pmul (q2) — NOT fused
    x   = __fadd_rn(x, y);                         // padd
    x   = __fadd_rn(x, y2);                        // padd
    return x;
}

__device__ __forceinline__ float log_expected_count(int id) {
    float idf = (float)id;                           // exact (id < 2^24)
    float l2 = eigen_plogf(__fadd_rn(idf, 2.0f));
    float l1 = eigen_plogf(__fadd_rn(idf, 1.0f));
    float num = __fsub_rn(l2, l1);                   // the f32 cancellation
    float logH = eigen_plogf(1000001.0f);
    float p = num / logH;
    float t = __fmul_rn(8192.0f, log1pf(-p));        // *2^13 exact
    float e = -expm1f(t);
    e = fmaxf(e, 1e-38f);
    return logf(e);
}

// Fragment layout: element (row, k) of a [N x 128] bf16 matrix lives at
// ushort offset ((row>>4)*4 + (k>>5))*512 + (((k>>3)&3)*16 + (row&15))*8 + (k&7).
// A wave's MFMA load for (tile, ks) is ONE coalesced 1KB read at
// (tile*4+ks)*512 + lane*8.
__device__ __forceinline__ size_t frag_off(int row, int k0) {
    return (size_t)(((row >> 4) * 4 + (k0 >> 5)) * 512) +
           ((((k0 >> 3) & 3) * 16 + (row & 15)) * 8) + (k0 & 7);
}

// ---- kernel 1: 256-thread blocks, 1 wave = 1 task.
//  task < BATCH: h-row (half-wave ctx split, float4 gathers) + true logit
//  task >= BATCH: TWO w-rows per wave (one per half), float4 gathers + bias
__global__ __launch_bounds__(256) void k_prep(
        const int* __restrict__ ids, const int* __restrict__ labels,
        const int* __restrict__ sampled,
        const float* __restrict__ in_emb, const float* __restrict__ out_emb,
        const float* __restrict__ bias,
        unsigned short* __restrict__ h_frag, unsigned short* __restrict__ w_frag,
        float* __restrict__ tl, float* __restrict__ sb) {
    int tid  = threadIdx.x;
    int lane = tid & 63;
    int wv   = tid >> 6;
    int task = blockIdx.x * 4 + wv;
    int half = lane >> 5;             // 0: lanes 0-31, 1: lanes 32-63
    int m    = lane & 31;             // dim group: dims 4m..4m+3
    int k0   = 4 * m;

    if (task < BATCH) {
        int b = task;
        float4 s4 = make_float4(0.f, 0.f, 0.f, 0.f);
#pragma unroll
        for (int c = 0; c < CTX; c += 2) {
            int id = ids[b * CTX + c + half];
            float4 v = *(const float4*)(in_emb + (size_t)id * DIM + k0);
            s4.x += v.x; s4.y += v.y; s4.z += v.z; s4.w += v.w;
        }
        // combine even-c (lower half) and odd-c (upper half) partials
        s4.x += __shfl_xor(s4.x, 32, 64);
        s4.y += __shfl_xor(s4.y, 32, 64);
        s4.z += __shfl_xor(s4.z, 32, 64);
        s4.w += __shfl_xor(s4.w, 32, 64);

        if (half == 0) {
            ushort4 hb;
            hb.x = f2bf(s4.x); hb.y = f2bf(s4.y); hb.z = f2bf(s4.z); hb.w = f2bf(s4.w);
            *(ushort4*)(h_frag + frag_off(b, k0)) = hb;
        }
        int lab = labels[b];
        float4 w4 = *(const float4*)(out_emb + (size_t)lab * DIM + k0);
        float prod = s4.x * w4.x + s4.y * w4.y + s4.z * w4.z + s4.w * w4.w;
#pragma unroll
        for (int mm = 16; mm > 0; mm >>= 1) prod += __shfl_xor(prod, mm, 64);
        if (lane == 0) tl[b] = prod + bias[lab] - log_expected_count(lab);
    } else {
        int s = (task - BATCH) * 2 + half;
        int sid = sampled[s];
        float4 v = *(const float4*)(out_emb + (size_t)sid * DIM + k0);
        ushort4 wb;
        wb.x = f2bf(v.x); wb.y = f2bf(v.y); wb.z = f2bf(v.z); wb.w = f2bf(v.w);
        *(ushort4*)(w_frag + frag_off(s, k0)) = wb;
        if (m == 0) sb[s] = bias[sid] - log_expected_count(sid);
    }
}

// ---- kernel 2: 256x128-tile bf16 MFMA GEMM fused with bias/mask/exp/row-sums.
//      4 waves x 64 rows (4 row-tiles) -> MFMA:ds_read = 4:1.
//      B slice (32KB) staged via global_load_lds (width 16).
__global__ __launch_bounds__(256, 2) void k_gemm_lse(
    const unsigned short* __restrict__ h_frag, const unsigned short* __restrict__ w_frag,
    const float* __restrict__ sb, const int* __restrict__ sampled,
    const int* __restrict__ labels, float* __restrict__ partials) {
    __shared__ __align__(16) unsigned short ldsb[16384];   // 32KB
    int tid  = threadIdx.x;
    int lane = tid & 63;
    int wv   = tid >> 6;
    int r16  = lane & 15;
    int kg   = lane >> 4;
    int rbase = blockIdx.x * 256 + wv * 64;
    int cbase = blockIdx.y * 128;

    // stage B via async global->LDS, 16B/lane, linear layout
    const unsigned short* wsrc = w_frag + (size_t)cbase * 128;
#pragma unroll
    for (int i = 0; i < 8; ++i) {
        int eo = (i * 256 + tid) * 8;            // ushort offset, lane-contiguous
        __builtin_amdgcn_global_load_lds(
            (const __attribute__((address_space(1))) unsigned int*)(wsrc + eo),
            (__attribute__((address_space(3))) unsigned int*)(ldsb + eo),
            16, 0, 0);
    }

    // A fragments: 4 row-tiles x 4 ks, coalesced 1KB wave-loads (L2-resident)
    short8 a[4][4];
#pragma unroll
    for (int rt = 0; rt < 4; ++rt)
#pragma unroll
        for (int ks = 0; ks < 4; ++ks)
            a[rt][ks] = *(const short8*)(h_frag +
                (size_t)((((rbase >> 4) + rt) * 4 + ks) * 512) + lane * 8);

    f32x4 acc[4][8];
#pragma unroll
    for (int rt = 0; rt < 4; ++rt)
#pragma unroll
        for (int t = 0; t < 8; ++t) acc[rt][t] = (f32x4){0.f, 0.f, 0.f, 0.f};

    __syncthreads();
#pragma unroll
    for (int t = 0; t < 8; ++t) {
#pragma unroll
        for (int ks = 0; ks < 4; ++ks) {
            short8 bv = *(const short8*)(ldsb + (t * 4 + ks) * 512 + lane * 8);
#pragma unroll
            for (int rt = 0; rt < 4; ++rt)
                acc[rt][t] = __builtin_amdgcn_mfma_f32_16x16x32_bf16(a[rt][ks], bv, acc[rt][t], 0, 0, 0);
        }
    }

    int lab[4][4];
    float rsum[4][4];
#pragma unroll
    for (int rt = 0; rt < 4; ++rt)
#pragma unroll
        for (int r = 0; r < 4; ++r) {
            lab[rt][r]  = labels[rbase + rt * 16 + kg * 4 + r];
            rsum[rt][r] = 0.f;
        }
#pragma unroll
    for (int t = 0; t < 8; ++t) {
        int col = cbase + t * 16 + r16;                   // C/D col = lane&15
        float sbv = sb[col];
        int   sid = sampled[col];
#pragma unroll
        for (int rt = 0; rt < 4; ++rt)
#pragma unroll
            for (int r = 0; r < 4; ++r) {
                float logit = acc[rt][t][r] + sbv;
                if (sid != lab[rt][r]) rsum[rt][r] += __expf(logit);
            }
    }
#pragma unroll
    for (int m = 1; m < 16; m <<= 1)
#pragma unroll
        for (int rt = 0; rt < 4; ++rt)
#pragma unroll
            for (int r = 0; r < 4; ++r)
                rsum[rt][r] += __shfl_xor(rsum[rt][r], m, 64);
    if (r16 == 0)
#pragma unroll
        for (int rt = 0; rt < 4; ++rt)
#pragma unroll
            for (int r = 0; r < 4; ++r)
                partials[(size_t)(rbase + rt * 16 + kg * 4 + r) * NCHUNK + blockIdx.y] = rsum[rt][r];
}

// ---- kernel 3: loss[b] = log(sum_chunks + exp(tl)) - tl
__global__ void k_reduce(const float* __restrict__ partials, const float* __restrict__ tl,
                         float* __restrict__ out) {
    int row  = blockIdx.x * 4 + (threadIdx.x >> 6);
    int lane = threadIdx.x & 63;
    float s = partials[(size_t)row * NCHUNK + lane];
#pragma unroll
    for (int m = 32; m > 0; m >>= 1) s += __shfl_xor(s, m, 64);
    if (lane == 0) {
        float t = tl[row];
        out[row] = logf(s + __expf(t)) - t;
    }
}

extern "C" void kernel_launch(void* const* d_in, const int* in_sizes, int n_in,
                              void* d_out, int out_size, void* d_ws, size_t ws_size,
                              hipStream_t stream) {
    const int*   ids     = (const int*)d_in[0];   // integers arrive as int32
    const int*   labels  = (const int*)d_in[1];
    const int*   sampled = (const int*)d_in[2];
    const float* in_emb  = (const float*)d_in[3];
    const float* out_emb = (const float*)d_in[4];
    const float* bias    = (const float*)d_in[5];
    float* out = (float*)d_out;

    char* ws = (char*)d_ws;
    unsigned short* h_frag = (unsigned short*)(ws);                     // 1 MB
    unsigned short* w_frag = (unsigned short*)(ws + (1u << 20));        // 2 MB
    float* tl       = (float*)(ws + 3u * (1u << 20));                   // 16 KB
    float* sb       = (float*)(ws + 3u * (1u << 20) + (1u << 16));      // 32 KB
    float* partials = (float*)(ws + 3u * (1u << 20) + (1u << 16) + (1u << 15)); // 1 MB

    // tasks: 4096 h-rows (1/wave) + 4096 w-pairs (2 rows/wave) = 8192 waves
    k_prep<<<dim3((BATCH + NSAMP / 2) / 4), dim3(256), 0, stream>>>(
        ids, labels, sampled, in_emb, out_emb, bias, h_frag, w_frag, tl, sb);
    k_gemm_lse<<<dim3(BATCH / 256, NSAMP / 128), dim3(256), 0, stream>>>(h_frag, w_frag, sb, sampled, labels, partials);
    k_reduce<<<dim3(BATCH / 4), dim3(256), 0, stream>>>(partials, tl, out);
}